// Round 8
// baseline (177.561 us; speedup 1.0000x reference)
//
#include <hip/hip_runtime.h>

typedef __bf16 bf16x8 __attribute__((ext_vector_type(8)));
typedef float f32x4 __attribute__((ext_vector_type(4)));

__device__ __forceinline__ void gload_lds16(const float* g, float* l) {
    __builtin_amdgcn_global_load_lds(
        (const __attribute__((address_space(1))) void*)g,
        (__attribute__((address_space(3))) void*)l, 16, 0, 0);
}

// ---------------------------------------------------------------------------
// Repack all three W [H=128][K] fp32 -> bf16 MFMA fragments ("A" operand):
// dst[((ks*8 + hf)*64 + lane)*8 + e] =
//   bf16(W[hf*16 + (lane&15)][ks*32 + (lane>>4)*8 + e])
// ---------------------------------------------------------------------------
__global__ void prep_all_kernel(const float* __restrict__ W0, const float* __restrict__ W1,
                                const float* __restrict__ W2,
                                __bf16* __restrict__ Bf0, __bf16* __restrict__ Bf1,
                                __bf16* __restrict__ Bf2) {
    int t = blockIdx.x * blockDim.x + threadIdx.x;
    const float* W;
    __bf16* dst;
    int K;
    if (t < 1024)      { W = W0; dst = Bf0; K = 64; }
    else if (t < 3072) { W = W1; dst = Bf1; K = 128; t -= 1024; }
    else if (t < 7168) { W = W2; dst = Bf2; K = 256; t -= 3072; }
    else return;
    int lane = t & 63;
    int hf = (t >> 6) & 7;
    int ks = t >> 9;
    int row = hf * 16 + (lane & 15);
    int k0 = ks * 32 + ((lane >> 4) << 3);
    const float* src = W + (size_t)row * K + k0;
    __bf16* d = dst + (size_t)t * 8;
#pragma unroll
    for (int e = 0; e < 8; ++e) d[e] = (__bf16)src[e];
}

// ---------------------------------------------------------------------------
// Whole-K staged variant. Wave owns 16 rows x 128 cols (1 M-frag x 8 N-frags).
// Stage: the wave's ENTIRE 16-row x-panel is read ONCE, fully sequentially
// (each global_load_lds covers 1KB contiguous), into a wave-private LDS slice.
// K-loop then reads x from LDS only; W (L2-resident frags) prefetched 1 deep
// in registers with counted vmcnt (never 0 until tail).
// Swizzle: LDS[row][u] = global unit u^(row&7) (16B units), applied on the
// global SOURCE (gload_lds dest must be linear) and on the ds_read address.
// ds_read bank check: addr/4 % 32 depends only on u (row stride 64/128/256
// floats = 0 mod 32) -> u^(row&7) spreads 16 lanes over 8 bank-groups, 2-way.
// ---------------------------------------------------------------------------
template <int K>
__device__ __forceinline__ void run_type(
    const float* __restrict__ x, const __bf16* __restrict__ Wfrag,
    const float* __restrict__ bias, const int* __restrict__ idx,
    float* __restrict__ out, int M, int blk, float* ldsw)
{
    constexpr int KSTEPS = K / 32;
    constexpr int UPR = K / 4;                 // 16B units per row
    constexpr int LUPR = (K == 256) ? 6 : (K == 128 ? 5 : 4);
    constexpr int NST = (16 * UPR) / 64;       // stage instructions (whole panel)
    const int lane = threadIdx.x & 63;
    const int wave = threadIdx.x >> 6;
    const int l15 = lane & 15;
    const int kg = lane >> 4;
    const int wrb = blk * 32 + wave * 16;      // wave's first global row

    // scatter index for this lane's row (pinned early)
    const int gr0 = wrb + l15;
    const int r0c = gr0 < M ? gr0 : M - 1;
    int orow0 = idx[r0c];
    asm volatile("" : "+v"(orow0));

    // --- stage the whole panel: fully sequential global reads ---
#pragma unroll
    for (int s = 0; s < NST; ++s) {
        int f = s * 64 + lane;                 // flat 16B-unit index in panel
        int row = f >> LUPR;
        int unit = f & (UPR - 1);
        int su = unit ^ (row & 7);             // inverse-swizzled source
        int grow = wrb + row;
        grow = grow < M ? grow : M - 1;
        gload_lds16(x + (size_t)grow * K + su * 4, ldsw + s * 256);
    }
    __builtin_amdgcn_sched_barrier(0);

    // --- W(0) prefetch ---
    const bf16x8* wbase = reinterpret_cast<const bf16x8*>(Wfrag) + lane;
    bf16x8 w[2][8];
#pragma unroll
    for (int hf = 0; hf < 8; ++hf) w[0][hf] = wbase[hf * 64];
    __builtin_amdgcn_sched_barrier(0);

    f32x4 acc[8] = {};
    const float* lrow = ldsw + l15 * K;

#pragma unroll
    for (int i = 0; i < KSTEPS; ++i) {
        // prefetch W(i+1); counted wait leaves it in flight
        if (i + 1 < KSTEPS) {
#pragma unroll
            for (int hf = 0; hf < 8; ++hf) w[(i + 1) & 1][hf] = wbase[((i + 1) * 8 + hf) * 64];
            __builtin_amdgcn_sched_barrier(0);
            asm volatile("s_waitcnt vmcnt(8)" ::: "memory");   // stage+W(i) done
        } else {
            __builtin_amdgcn_sched_barrier(0);
            asm volatile("s_waitcnt vmcnt(0)" ::: "memory");
        }
        __builtin_amdgcn_sched_barrier(0);
        const int u0 = (i * 8 + 2 * kg) ^ (l15 & 7);
        const int u1 = (i * 8 + 2 * kg + 1) ^ (l15 & 7);
        f32x4 p0 = *(const f32x4*)(lrow + u0 * 4);
        f32x4 p1 = *(const f32x4*)(lrow + u1 * 4);
        bf16x8 xf;
        xf[0] = (__bf16)p0[0]; xf[1] = (__bf16)p0[1]; xf[2] = (__bf16)p0[2]; xf[3] = (__bf16)p0[3];
        xf[4] = (__bf16)p1[0]; xf[5] = (__bf16)p1[1]; xf[6] = (__bf16)p1[2]; xf[7] = (__bf16)p1[3];
#pragma unroll
        for (int hf = 0; hf < 8; ++hf)
            acc[hf] = __builtin_amdgcn_mfma_f32_16x16x32_bf16(w[i & 1][hf], xf, acc[hf], 0, 0, 0);
    }

    // --- epilogue: bias + contiguous f32x4 scatter stores ---
    if (gr0 < M) {
#pragma unroll
        for (int hf = 0; hf < 8; ++hf) {
            f32x4 bv = *reinterpret_cast<const f32x4*>(bias + hf * 16 + kg * 4);
            f32x4 v = acc[hf] + bv;
            *reinterpret_cast<f32x4*>(out + (size_t)orow0 * 128 + hf * 16 + kg * 4) = v;
        }
    }
}

// Fused: one grid covers all three types. Longest-K type first (better tail).
__global__ __launch_bounds__(128, 2) void fused_linear_kernel(
    const float* __restrict__ x0, const float* __restrict__ x1, const float* __restrict__ x2,
    const __bf16* __restrict__ Bf0, const __bf16* __restrict__ Bf1, const __bf16* __restrict__ Bf2,
    const float* __restrict__ b0, const float* __restrict__ b1, const float* __restrict__ b2,
    const int* __restrict__ idx0, const int* __restrict__ idx1, const int* __restrict__ idx2,
    float* __restrict__ out, int M0, int M1, int M2, int nb2, int nb21)
{
    __shared__ float lds[2][4096];   // 32 KB: 2 waves x 16 rows x up-to-256 floats
    int b = blockIdx.x;
    float* ldsw = lds[threadIdx.x >> 6];
    if (b < nb2)       run_type<256>(x2, Bf2, b2, idx2, out, M2, b, ldsw);
    else if (b < nb21) run_type<128>(x1, Bf1, b1, idx1, out, M1, b - nb2, ldsw);
    else               run_type<64>(x0, Bf0, b0, idx0, out, M0, b - nb21, ldsw);
}

extern "C" void kernel_launch(void* const* d_in, const int* in_sizes, int n_in,
                              void* d_out, int out_size, void* d_ws, size_t ws_size,
                              hipStream_t stream) {
    const float* x0 = (const float*)d_in[0];
    const float* x1 = (const float*)d_in[1];
    const float* x2 = (const float*)d_in[2];
    const float* W0 = (const float*)d_in[3];
    const float* b0 = (const float*)d_in[4];
    const float* W1 = (const float*)d_in[5];
    const float* b1 = (const float*)d_in[6];
    const float* W2 = (const float*)d_in[7];
    const float* b2 = (const float*)d_in[8];
    const int* idx0 = (const int*)d_in[9];
    const int* idx1 = (const int*)d_in[10];
    const int* idx2 = (const int*)d_in[11];
    float* out = (float*)d_out;

    const int M0 = in_sizes[9];
    const int M1 = in_sizes[10];
    const int M2 = in_sizes[11];

    __bf16* Bf0 = (__bf16*)d_ws;              // K=64:  8192 bf16
    __bf16* Bf1 = Bf0 + 2 * 8 * 64 * 8;       // K=128: 16384 bf16
    __bf16* Bf2 = Bf1 + 4 * 8 * 64 * 8;       // K=256: 32768 bf16

    prep_all_kernel<<<(7168 + 255) / 256, 256, 0, stream>>>(W0, W1, W2, Bf0, Bf1, Bf2);

    const int nb0 = (M0 + 31) / 32;
    const int nb1 = (M1 + 31) / 32;
    const int nb2 = (M2 + 31) / 32;
    fused_linear_kernel<<<nb0 + nb1 + nb2, 128, 0, stream>>>(
        x0, x1, x2, Bf0, Bf1, Bf2, b0, b1, b2, idx0, idx1, idx2,
        out, M0, M1, M2, nb2, nb2 + nb1);
}

// Round 9
// 168.685 us; speedup vs baseline: 1.0526x; 1.0526x over previous
//
#include <hip/hip_runtime.h>

typedef __bf16 bf16x8 __attribute__((ext_vector_type(8)));
typedef float f32x4 __attribute__((ext_vector_type(4)));

__device__ __forceinline__ void gload_lds16(const void* g, void* l) {
    __builtin_amdgcn_global_load_lds(
        (const __attribute__((address_space(1))) void*)g,
        (__attribute__((address_space(3))) void*)l, 16, 0, 0);
}

// ---------------------------------------------------------------------------
// Repack all three W [H=128][K] fp32 -> bf16 MFMA fragments ("A" operand):
// dst[((ks*8 + hf)*64 + lane)*8 + e] =
//   bf16(W[hf*16 + (lane&15)][ks*32 + (lane>>4)*8 + e])
// ---------------------------------------------------------------------------
__global__ void prep_all_kernel(const float* __restrict__ W0, const float* __restrict__ W1,
                                const float* __restrict__ W2,
                                __bf16* __restrict__ Bf0, __bf16* __restrict__ Bf1,
                                __bf16* __restrict__ Bf2) {
    int t = blockIdx.x * blockDim.x + threadIdx.x;
    const float* W;
    __bf16* dst;
    int K;
    if (t < 1024)      { W = W0; dst = Bf0; K = 64; }
    else if (t < 3072) { W = W1; dst = Bf1; K = 128; t -= 1024; }
    else if (t < 7168) { W = W2; dst = Bf2; K = 256; t -= 3072; }
    else return;
    int lane = t & 63;
    int hf = (t >> 6) & 7;
    int ks = t >> 9;
    int row = hf * 16 + (lane & 15);
    int k0 = ks * 32 + ((lane >> 4) << 3);
    const float* src = W + (size_t)row * K + k0;
    __bf16* d = dst + (size_t)t * 8;
#pragma unroll
    for (int e = 0; e < 8; ++e) d[e] = (__bf16)src[e];
}

// ---------------------------------------------------------------------------
// W-in-LDS variant. The recurring per-k-step global round trip (8 W-frag L2
// loads) is replaced by conflict-free ds_read_b128 from a 32 KB LDS copy of
// the W-frag array, staged cooperatively ONCE per block via global_load_lds
// (K=256 stages in 2 phases of 32 KB). The only remaining global loads in the
// K-loop are x (4 per k-step), covered by a 2-deep register prefetch ring.
// Wave = 32 rows x 128 cols (2 M-frags x 8 N-frags), block = 4 waves.
// ---------------------------------------------------------------------------
template <int K>
__device__ __forceinline__ void run_type(
    const float* __restrict__ x, const __bf16* __restrict__ Wfrag,
    const float* __restrict__ bias, const int* __restrict__ idx,
    float* __restrict__ out, int M, int blk, __bf16* ldsW)
{
    constexpr int KSTEPS = K / 32;
    constexpr int PHASES = (K == 256) ? 2 : 1;
    constexpr int KSP = KSTEPS / PHASES;            // k-steps per phase
    constexpr int PHASE_BYTES = KSP * 8 * 64 * 16;  // <= 32768
    constexpr int NST = PHASE_BYTES / (256 * 16);   // stage insts per thread

    const int tid = threadIdx.x;
    const int lane = tid & 63;
    const int wave = tid >> 6;
    const int l15 = lane & 15;
    const int kg = lane >> 4;
    const int rowbase = blk * 128 + wave * 32;

    const int gr0 = rowbase + l15;
    const int gr1 = gr0 + 16;
    const int r0c = gr0 < M ? gr0 : M - 1;
    const int r1c = gr1 < M ? gr1 : M - 1;
    int orow0 = idx[r0c];
    int orow1 = idx[r1c];
    asm volatile("" : "+v"(orow0), "+v"(orow1));   // pin idx loads in prologue

    const float* a0p = x + (size_t)r0c * K + kg * 8;
    const float* a1p = x + (size_t)r1c * K + kg * 8;

    // x prefetch ring (statically indexed: loops fully unrolled)
    f32x4 xs[3][4];
    auto ldx = [&](int i) {
        int ii = i < KSTEPS ? i : KSTEPS - 1;       // clamped tail re-load (L2 hit)
        f32x4* s = xs[i % 3];
        s[0] = *(const f32x4*)(a0p + ii * 32);
        s[1] = *(const f32x4*)(a0p + ii * 32 + 4);
        s[2] = *(const f32x4*)(a1p + ii * 32);
        s[3] = *(const f32x4*)(a1p + ii * 32 + 4);
    };

    auto stageW = [&](int ph) {
        const char* src = (const char*)Wfrag + (size_t)ph * PHASE_BYTES;
        char* dst = (char*)ldsW;
#pragma unroll
        for (int s = 0; s < NST; ++s)
            gload_lds16(src + (s * 256 + tid) * 16, dst + (s * 256 + tid) * 16);
    };

    f32x4 acc[2][8] = {};

    // --- prologue: x(0), x(1) in flight; stage W phase 0; drain; sync ---
    ldx(0);
    ldx(1);
    stageW(0);
    asm volatile("s_waitcnt vmcnt(0)" ::: "memory");
    __builtin_amdgcn_sched_barrier(0);
    __syncthreads();

#pragma unroll
    for (int p = 0; p < PHASES; ++p) {
        if (p > 0) {
            __syncthreads();                        // all waves done reading prev phase
            stageW(p);
            asm volatile("s_waitcnt vmcnt(0)" ::: "memory");
            __builtin_amdgcn_sched_barrier(0);
            __syncthreads();
        }
#pragma unroll
        for (int j = 0; j < KSP; ++j) {
            const int i = p * KSP + j;
            // issue x(i+2) first (independent; stays in flight through this step)
            ldx(i + 2);
            // convert current x (auto-waits only on slot i%3)
            const f32x4* cu = xs[i % 3];
            bf16x8 xf0, xf1;
            xf0[0] = (__bf16)cu[0][0]; xf0[1] = (__bf16)cu[0][1]; xf0[2] = (__bf16)cu[0][2]; xf0[3] = (__bf16)cu[0][3];
            xf0[4] = (__bf16)cu[1][0]; xf0[5] = (__bf16)cu[1][1]; xf0[6] = (__bf16)cu[1][2]; xf0[7] = (__bf16)cu[1][3];
            xf1[0] = (__bf16)cu[2][0]; xf1[1] = (__bf16)cu[2][1]; xf1[2] = (__bf16)cu[2][2]; xf1[3] = (__bf16)cu[2][3];
            xf1[4] = (__bf16)cu[3][0]; xf1[5] = (__bf16)cu[3][1]; xf1[6] = (__bf16)cu[3][2]; xf1[7] = (__bf16)cu[3][3];
            // W from LDS (consecutive 16B/lane -> conflict-free) + MFMA
            const __bf16* wl = ldsW + ((size_t)j * 8 * 64 + lane) * 8;
#pragma unroll
            for (int hf = 0; hf < 8; ++hf) {
                bf16x8 w = *(const bf16x8*)(wl + (size_t)hf * 64 * 8);
                acc[0][hf] = __builtin_amdgcn_mfma_f32_16x16x32_bf16(w, xf0, acc[0][hf], 0, 0, 0);
                acc[1][hf] = __builtin_amdgcn_mfma_f32_16x16x32_bf16(w, xf1, acc[1][hf], 0, 0, 0);
            }
        }
    }

    // --- epilogue: bias + contiguous f32x4 scatter stores ---
#pragma unroll
    for (int hf = 0; hf < 8; ++hf) {
        f32x4 bv = *reinterpret_cast<const f32x4*>(bias + hf * 16 + kg * 4);
        if (gr0 < M) {
            f32x4 v = acc[0][hf] + bv;
            *reinterpret_cast<f32x4*>(out + (size_t)orow0 * 128 + hf * 16 + kg * 4) = v;
        }
        if (gr1 < M) {
            f32x4 v = acc[1][hf] + bv;
            *reinterpret_cast<f32x4*>(out + (size_t)orow1 * 128 + hf * 16 + kg * 4) = v;
        }
    }
}

// Fused: one grid covers all three types. Longest-K type first (better tail).
__global__ __launch_bounds__(256, 3) void fused_linear_kernel(
    const float* __restrict__ x0, const float* __restrict__ x1, const float* __restrict__ x2,
    const __bf16* __restrict__ Bf0, const __bf16* __restrict__ Bf1, const __bf16* __restrict__ Bf2,
    const float* __restrict__ b0, const float* __restrict__ b1, const float* __restrict__ b2,
    const int* __restrict__ idx0, const int* __restrict__ idx1, const int* __restrict__ idx2,
    float* __restrict__ out, int M0, int M1, int M2, int nb2, int nb21)
{
    __shared__ __bf16 ldsW[16384];   // 32 KB: one W phase
    int b = blockIdx.x;
    if (b < nb2)       run_type<256>(x2, Bf2, b2, idx2, out, M2, b, ldsW);
    else if (b < nb21) run_type<128>(x1, Bf1, b1, idx1, out, M1, b - nb2, ldsW);
    else               run_type<64>(x0, Bf0, b0, idx0, out, M0, b - nb21, ldsW);
}

extern "C" void kernel_launch(void* const* d_in, const int* in_sizes, int n_in,
                              void* d_out, int out_size, void* d_ws, size_t ws_size,
                              hipStream_t stream) {
    const float* x0 = (const float*)d_in[0];
    const float* x1 = (const float*)d_in[1];
    const float* x2 = (const float*)d_in[2];
    const float* W0 = (const float*)d_in[3];
    const float* b0 = (const float*)d_in[4];
    const float* W1 = (const float*)d_in[5];
    const float* b1 = (const float*)d_in[6];
    const float* W2 = (const float*)d_in[7];
    const float* b2 = (const float*)d_in[8];
    const int* idx0 = (const int*)d_in[9];
    const int* idx1 = (const int*)d_in[10];
    const int* idx2 = (const int*)d_in[11];
    float* out = (float*)d_out;

    const int M0 = in_sizes[9];
    const int M1 = in_sizes[10];
    const int M2 = in_sizes[11];

    __bf16* Bf0 = (__bf16*)d_ws;              // K=64:  8192 bf16
    __bf16* Bf1 = Bf0 + 2 * 8 * 64 * 8;       // K=128: 16384 bf16
    __bf16* Bf2 = Bf1 + 4 * 8 * 64 * 8;       // K=256: 32768 bf16

    prep_all_kernel<<<(7168 + 255) / 256, 256, 0, stream>>>(W0, W1, W2, Bf0, Bf1, Bf2);

    const int nb0 = (M0 + 127) / 128;
    const int nb1 = (M1 + 127) / 128;
    const int nb2 = (M2 + 127) / 128;
    fused_linear_kernel<<<nb0 + nb1 + nb2, 256, 0, stream>>>(
        x0, x1, x2, Bf0, Bf1, Bf2, b0, b1, b2, idx0, idx1, idx2,
        out, M0, M1, M2, nb2, nb2 + nb1);
}